// Round 12
// baseline (42.773 us; speedup 1.0000x reference)
//
#include <hip/hip_runtime.h>
#include <math.h>

#define TSTEPS 11
#define GPW 7          // 9-lane groups per wave
#define PPB 14         // problems per block: each group handles 2 (A: slot g, B: slot 7+g)
#define LPP 9
#define IN_STRIDE 228  // floats per input slot (228%32=4 -> bank stagger); step t at t*20
#define WSTRIDE 228    // floats per work slot
#define PHT_OFF 0
#define S6_OFF 144
#define Y_OFF 192
#define EST_OFF 200

// single-wave block: RAW needs wave-level lgkmcnt drain; WAR only a compiler fence
#define FENCE_RAW() asm volatile("s_waitcnt lgkmcnt(0)" ::: "memory")
#define FENCE_WAR() asm volatile("" ::: "memory")

__device__ __forceinline__ float sel3(int c, float a, float b, float d) {
    float t = (c == 1) ? b : a;
    return (c == 2) ? d : t;
}
__device__ __forceinline__ size_t umin_sz(size_t a, size_t b) { return a < b ? a : b; }

struct SP {    // per-problem per-step parameters
    float dt, hdt2, w0, w1, w2;
    float Rm[9], E[9], N[9], M2[9];
};
struct UP {    // per-problem update-phase operands
    float h0v[9], h1v[9], hr0, hr1, hr2, sdv, rsa, rsb, velv;
};

__global__ void __launch_bounds__(64)
ekf_kernel(const float* __restrict__ dts, const float* __restrict__ wa,
           const float* __restrict__ Rc, const float* __restrict__ vel,
           const float* __restrict__ grav, const float* __restrict__ H0g,
           const float* __restrict__ H1g, const float* __restrict__ prot,
           const float* __restrict__ ptrans, const float* __restrict__ vrot,
           const float* __restrict__ vtrans, const float* __restrict__ vrstd,
           const float* __restrict__ vtstd, const float* __restrict__ icds,
           const float* __restrict__ inw, float* __restrict__ out, int B)
{
    __shared__ __align__(16) float gin[PPB * IN_STRIDE];   // 12768 B
    __shared__ __align__(16) float lds[PPB * WSTRIDE];     // 12768 B
    const int tid = threadIdx.x;
    const int praw = tid / LPP;
    const int r = tid - praw * LPP;            // 0..8
    const int g = (praw < GPW) ? praw : (GPW - 1);
    const int blk0 = blockIdx.x * PPB;
    const int bA0 = blk0 + g, bB0 = blk0 + GPW + g;
    const bool validA = (praw < GPW) && (bA0 < B);
    const bool validB = (praw < GPW) && (bB0 < B);
    const int bA = (bA0 < B) ? bA0 : (B - 1);
    const int bB = (bB0 < B) ? bB0 : (B - 1);
    float* LA = lds + g * WSTRIDE;
    float* LB = lds + (GPW + g) * WSTRIDE;
    const float* giA = gin + g * IN_STRIDE;
    const float* giB = gin + (GPW + g) * IN_STRIDE;

    // ---- block-coalesced preload of step inputs (slot pp <-> problem blk0+pp)
    {
        const size_t dmax = (size_t)B * 11 - 1;
        for (int e = tid; e < PPB * 11; e += 64) {
            const int pp = e / 11, o = e - pp * 11;
            gin[pp * IN_STRIDE + o * 20] = dts[umin_sz((size_t)blk0 * 11 + (size_t)pp * 11 + o, dmax)];
        }
        const size_t wmax = (size_t)B * 72 - 1;
        for (int e = tid; e < PPB * 66; e += 64) {           // 11 steps x 6
            const int pp = e / 66, o = e - pp * 66;
            const int t = o / 6, k = o - t * 6;
            gin[pp * IN_STRIDE + t * 20 + 2 + k] =
                wa[umin_sz((size_t)blk0 * 72 + (size_t)pp * 72 + o, wmax)];
        }
        const size_t rmax = (size_t)B * 108 - 1;
        for (int e = tid; e < PPB * 99; e += 64) {           // 11 steps x 9
            const int pp = e / 99, o = e - pp * 99;
            const int t = o / 9, k = o - t * 9;
            gin[pp * IN_STRIDE + t * 20 + 8 + k] =
                Rc[umin_sz((size_t)blk0 * 108 + (size_t)pp * 108 + o, rmax)];
        }
    }

    const float qcA = 1e-7f * exp10f(4.f * tanhf(inw[0]));
    const float qcB = 1e-7f * exp10f(4.f * tanhf(inw[1]));
    const float qcC = 1e-2f * exp10f(4.f * tanhf(inw[2]));
    const float qcD = 1e-3f * exp10f(4.f * tanhf(inw[3]));

    const float gA0 = grav[(size_t)bA*3+0], gA1 = grav[(size_t)bA*3+1], gA2 = grav[(size_t)bA*3+2];
    const float gB0 = grav[(size_t)bB*3+0], gB1 = grav[(size_t)bB*3+1], gB2 = grav[(size_t)bB*3+2];

    // per-problem state: np = P[:,r]; ncr = P[0:9,9+r]; d_br = P[9+r][9+r]
    // (bottom-right 9x9 of P stays EXACTLY diagonal — R10-validated)
    float npA[18], ncrA[9], d_brA, npB[18], ncrB[9], d_brB;
#pragma unroll
    for (int k = 0; k < 18; ++k) { npA[k] = 0.f; npB[k] = 0.f; }
#pragma unroll
    for (int k = 0; k < 9; ++k) { ncrA[k] = 0.f; ncrB[k] = 0.f; }
    { const float d0 = icds[r];     npA[r] = d0*d0 + 1e-12f; npB[r] = npA[r];
      const float d1 = icds[9 + r]; d_brA  = d1*d1 + 1e-12f; d_brB = d_brA; }

    const int cls = (r < 3) ? 0 : ((r < 6) ? 1 : 2);
    const int c3 = r - 3 * cls;

    FENCE_RAW();   // staging visible (single-wave block)

    // ---- per-step parameter build (E/N/M2 from LDS inputs)
    auto load_sp = [&](const float* gi, int t, float q0, float q1, float q2, SP& s) {
        const int o = t * 20;
        s.dt = gi[o];
        const float2 qa = *(const float2*)&gi[o + 2];
        const float2 qb = *(const float2*)&gi[o + 4];
        const float2 qc = *(const float2*)&gi[o + 6];
        s.w0 = qa.x; s.w1 = qa.y; s.w2 = qb.x;
        const float ar0 = qb.y, ar1 = qc.x, ar2 = qc.y;
        const float4 r0 = *(const float4*)&gi[o + 8];
        const float4 r1 = *(const float4*)&gi[o + 12];
        s.Rm[0]=r0.x; s.Rm[1]=r0.y; s.Rm[2]=r0.z; s.Rm[3]=r0.w;
        s.Rm[4]=r1.x; s.Rm[5]=r1.y; s.Rm[6]=r1.z; s.Rm[7]=r1.w;
        s.Rm[8]=gi[o + 16];
        s.hdt2 = 0.5f * s.dt * s.dt;
        const float Rg0 = s.Rm[0]*q0 + s.Rm[3]*q1 + s.Rm[6]*q2;
        const float Rg1 = s.Rm[1]*q0 + s.Rm[4]*q1 + s.Rm[7]*q2;
        const float Rg2 = s.Rm[2]*q0 + s.Rm[5]*q1 + s.Rm[8]*q2;
        const float a0 = Rg0 + (ar0 - Rg0);
        const float a1 = Rg1 + (ar1 - Rg1);
        const float a2 = Rg2 + (ar2 - Rg2);
        const float p0 = s.dt*s.w0, p1 = s.dt*s.w1, p2 = s.dt*s.w2;
        const float th2 = p0*p0 + p1*p1 + p2*p2;
        const float th4 = th2 * th2;
        const float A  = 1.f - th2*(1.f/6.f)  + th4*(1.f/120.f);
        const float Bc = 0.5f - th2*(1.f/24.f) + th4*(1.f/720.f);
        s.E[0] =  Bc*(p0*p0 - th2);  s.E[1] =  A*p2 + Bc*p0*p1;  s.E[2] = -A*p1 + Bc*p0*p2;
        s.E[3] = -A*p2 + Bc*p1*p0;   s.E[4] =  Bc*(p1*p1 - th2); s.E[5] =  A*p0 + Bc*p1*p2;
        s.E[6] =  A*p1 + Bc*p2*p0;   s.E[7] = -A*p0 + Bc*p2*p1;  s.E[8] =  Bc*(p2*p2 - th2);
        s.N[0] = -(s.Rm[1]*a2 - s.Rm[2]*a1); s.N[1] = -(s.Rm[2]*a0 - s.Rm[0]*a2); s.N[2] = -(s.Rm[0]*a1 - s.Rm[1]*a0);
        s.N[3] = -(s.Rm[4]*a2 - s.Rm[5]*a1); s.N[4] = -(s.Rm[5]*a0 - s.Rm[3]*a2); s.N[5] = -(s.Rm[3]*a1 - s.Rm[4]*a0);
        s.N[6] = -(s.Rm[7]*a2 - s.Rm[8]*a1); s.N[7] = -(s.Rm[8]*a0 - s.Rm[6]*a2); s.N[8] = -(s.Rm[6]*a1 - s.Rm[7]*a0);
#pragma unroll
        for (int c = 0; c < 3; ++c) {
            const float n0 = s.N[c*3], n1 = s.N[c*3+1], n2 = s.N[c*3+2];
            s.M2[c*3+0] = s.dt*n0 - s.hdt2*(n1*s.w2 - n2*s.w1);
            s.M2[c*3+1] = s.dt*n1 - s.hdt2*(n2*s.w0 - n0*s.w2);
            s.M2[c*3+2] = s.dt*n2 - s.hdt2*(n0*s.w1 - n1*s.w0);
        }
    };

    auto Smv = [&](const SP& s, const float v[18], float o[9]) {
        const float ev0 = s.E[0]*v[0] + s.E[1]*v[1] + s.E[2]*v[2];
        const float ev1 = s.E[3]*v[0] + s.E[4]*v[1] + s.E[5]*v[2];
        const float ev2 = s.E[6]*v[0] + s.E[7]*v[1] + s.E[8]*v[2];
        const float cx0 = s.w1*v[14] - s.w2*v[13];
        const float cx1 = s.w2*v[12] - s.w0*v[14];
        const float cx2 = s.w0*v[13] - s.w1*v[12];
        o[0] = ev0 - s.dt*v[12] + s.hdt2*cx0;
        o[1] = ev1 - s.dt*v[13] + s.hdt2*cx1;
        o[2] = ev2 - s.dt*v[14] + s.hdt2*cx2;
        const float nv0 = s.N[0]*v[0] + s.N[1]*v[1] + s.N[2]*v[2];
        const float nv1 = s.N[3]*v[0] + s.N[4]*v[1] + s.N[5]*v[2];
        const float nv2 = s.N[6]*v[0] + s.N[7]*v[1] + s.N[8]*v[2];
        const float rv0 = s.Rm[0]*v[15] + s.Rm[1]*v[16] + s.Rm[2]*v[17];
        const float rv1 = s.Rm[3]*v[15] + s.Rm[4]*v[16] + s.Rm[5]*v[17];
        const float rv2 = s.Rm[6]*v[15] + s.Rm[7]*v[16] + s.Rm[8]*v[17];
        o[3] = s.hdt2*nv0 + s.dt*v[6] - s.hdt2*v[9]  - s.hdt2*rv0;
        o[4] = s.hdt2*nv1 + s.dt*v[7] - s.hdt2*v[10] - s.hdt2*rv1;
        o[5] = s.hdt2*nv2 + s.dt*v[8] - s.hdt2*v[11] - s.hdt2*rv2;
        const float mv0 = s.M2[0]*v[0] + s.M2[1]*v[1] + s.M2[2]*v[2];
        const float mv1 = s.M2[3]*v[0] + s.M2[4]*v[1] + s.M2[5]*v[2];
        const float mv2 = s.M2[6]*v[0] + s.M2[7]*v[1] + s.M2[8]*v[2];
        const float nw0 = s.N[0]*v[12] + s.N[1]*v[13] + s.N[2]*v[14];
        const float nw1 = s.N[3]*v[12] + s.N[4]*v[13] + s.N[5]*v[14];
        const float nw2 = s.N[6]*v[12] + s.N[7]*v[13] + s.N[8]*v[14];
        o[6] = mv0 - s.dt*v[9]  - s.hdt2*nw0 - s.dt*rv0;
        o[7] = mv1 - s.dt*v[10] - s.hdt2*nw1 - s.dt*rv1;
        o[8] = mv2 - s.dt*v[11] - s.hdt2*nw2 - s.dt*rv2;
    };

    // U column 9+r = S * (ncr ; d_br*e_{9+r})  — bb block diagonal (exact)
    auto ucb_col = [&](const SP& s, const float ncr[9], float d_br, float ucb[9]) {
        const float colR0 = sel3(c3, s.Rm[0], s.Rm[1], s.Rm[2]);
        const float colR1 = sel3(c3, s.Rm[3], s.Rm[4], s.Rm[5]);
        const float colR2 = sel3(c3, s.Rm[6], s.Rm[7], s.Rm[8]);
        const float colN0 = sel3(c3, s.N[0], s.N[1], s.N[2]);
        const float colN1 = sel3(c3, s.N[3], s.N[4], s.N[5]);
        const float colN2 = sel3(c3, s.N[6], s.N[7], s.N[8]);
        const float colK0 = sel3(c3, 0.f, -s.w2,  s.w1);
        const float colK1 = sel3(c3,  s.w2, 0.f, -s.w0);
        const float colK2 = sel3(c3, -s.w1,  s.w0, 0.f);
        const float e0c = (c3 == 0) ? 1.f : 0.f;
        const float e1c = (c3 == 1) ? 1.f : 0.f;
        const float e2c = (c3 == 2) ? 1.f : 0.f;
        const float dbdt = d_br * s.dt, dbh = d_br * s.hdt2;
        const float s00 = (cls == 1) ? (-dbdt*e0c + dbh*colK0) : 0.f;
        const float s01 = (cls == 1) ? (-dbdt*e1c + dbh*colK1) : 0.f;
        const float s02 = (cls == 1) ? (-dbdt*e2c + dbh*colK2) : 0.f;
        const float s30 = (cls == 0) ? -dbh*e0c : ((cls == 2) ? -dbh*colR0 : 0.f);
        const float s31 = (cls == 0) ? -dbh*e1c : ((cls == 2) ? -dbh*colR1 : 0.f);
        const float s32 = (cls == 0) ? -dbh*e2c : ((cls == 2) ? -dbh*colR2 : 0.f);
        const float s60 = (cls == 0) ? -dbdt*e0c : ((cls == 1) ? -dbh*colN0 : -dbdt*colR0);
        const float s61 = (cls == 0) ? -dbdt*e1c : ((cls == 1) ? -dbh*colN1 : -dbdt*colR1);
        const float s62 = (cls == 0) ? -dbdt*e2c : ((cls == 1) ? -dbh*colN2 : -dbdt*colR2);
        ucb[0] = s.E[0]*ncr[0] + s.E[1]*ncr[1] + s.E[2]*ncr[2] + s00;
        ucb[1] = s.E[3]*ncr[0] + s.E[4]*ncr[1] + s.E[5]*ncr[2] + s01;
        ucb[2] = s.E[6]*ncr[0] + s.E[7]*ncr[1] + s.E[8]*ncr[2] + s02;
        ucb[3] = s.hdt2*(s.N[0]*ncr[0] + s.N[1]*ncr[1] + s.N[2]*ncr[2]) + s.dt*ncr[6] + s30;
        ucb[4] = s.hdt2*(s.N[3]*ncr[0] + s.N[4]*ncr[1] + s.N[5]*ncr[2]) + s.dt*ncr[7] + s31;
        ucb[5] = s.hdt2*(s.N[6]*ncr[0] + s.N[7]*ncr[1] + s.N[8]*ncr[2]) + s.dt*ncr[8] + s32;
        ucb[6] = s.M2[0]*ncr[0] + s.M2[1]*ncr[1] + s.M2[2]*ncr[2] + s60;
        ucb[7] = s.M2[3]*ncr[0] + s.M2[4]*ncr[1] + s.M2[5]*ncr[2] + s61;
        ucb[8] = s.M2[6]*ncr[0] + s.M2[7]*ncr[1] + s.M2[8]*ncr[2] + s62;
    };

    auto phaseB = [&](const SP& s, float* L, const float uca[9], const float ucb[9],
                      float np[18], float ncr[9], float& d_br) {
        float ur[18];
        {
            const float4* up = (const float4*)&L[r*20];
            const float4 q0 = up[0], q1 = up[1], q2 = up[2], q3 = up[3];
            const float2 q4 = *(const float2*)&L[r*20 + 16];
            ur[0]=q0.x; ur[1]=q0.y; ur[2]=q0.z; ur[3]=q0.w;
            ur[4]=q1.x; ur[5]=q1.y; ur[6]=q1.z; ur[7]=q1.w;
            ur[8]=q2.x; ur[9]=q2.y; ur[10]=q2.z; ur[11]=q2.w;
            ur[12]=q3.x; ur[13]=q3.y; ur[14]=q3.z; ur[15]=q3.w;
            ur[16]=q4.x; ur[17]=q4.y;
        }
        // Q ≈ G qc Gᵀ dt (R8-validated): col r needs qcC·(R Rᵀ) col for r>=6
        const float rc0 = sel3(c3, s.Rm[0], s.Rm[3], s.Rm[6]);
        const float rc1 = sel3(c3, s.Rm[1], s.Rm[4], s.Rm[7]);
        const float rc2 = sel3(c3, s.Rm[2], s.Rm[5], s.Rm[8]);
        const float dq = s.dt * qcC;
        const float q0v = dq * (s.Rm[0]*rc0 + s.Rm[1]*rc1 + s.Rm[2]*rc2);
        const float q1v = dq * (s.Rm[3]*rc0 + s.Rm[4]*rc1 + s.Rm[5]*rc2);
        const float q2v = dq * (s.Rm[6]*rc0 + s.Rm[7]*rc1 + s.Rm[8]*rc2);
        float w9[9];
        Smv(s, ur, w9);
#pragma unroll
        for (int i = 0; i < 9; ++i) np[i] = np[i] + uca[i] + ur[i] + w9[i];
        if (r < 3) np[r] += s.dt * qcA;
        if (r >= 6) { np[6] += q0v; np[7] += q1v; np[8] += q2v; }
#pragma unroll
        for (int i = 9; i < 18; ++i) np[i] += ur[i];
#pragma unroll
        for (int i = 0; i < 9; ++i) ncr[i] += ucb[i];
        if (r >= 3) d_br += s.dt * ((r < 6) ? qcB : qcD);
    };

    // ================= scan: two independent problems interleaved =================
    for (int t = 0; t < TSTEPS; ++t) {
        SP sA, sB;
        load_sp(giA, t, gA0, gA1, gA2, sA);
        load_sp(giB, t, gB0, gB1, gB2, sB);
        float ucaA[9], ucbA[9], ucaB[9], ucbB[9];
        Smv(sA, npA, ucaA);
        ucb_col(sA, ncrA, d_brA, ucbA);
        Smv(sB, npB, ucaB);
        ucb_col(sB, ncrB, d_brB, ucbB);
#pragma unroll
        for (int i = 0; i < 9; ++i) {
            LA[i*20 + r]     = ucaA[i];
            LA[i*20 + 9 + r] = ucbA[i];
            LB[i*20 + r]     = ucaB[i];
            LB[i*20 + 9 + r] = ucbB[i];
        }
        FENCE_RAW();
        phaseB(sA, LA, ucaA, ucbA, npA, ncrA, d_brA);
        phaseB(sB, LB, ucaB, ucbB, npB, ncrB, d_brB);
        FENCE_WAR();   // same-wave LDS pipe is in-order: WAR needs compiler fence only
    }

    // ================= update =================
    auto load_up = [&](int b, UP& u) {
#pragma unroll
        for (int i = 0; i < 9; ++i) { u.h0v[i] = H0g[(size_t)b*9 + i]; u.h1v[i] = H1g[(size_t)b*9 + i]; }
        const int rc6 = (r < 6) ? r : 5;
        const float* hpr = (rc6 < 3) ? (H0g + (size_t)b*9 + rc6*3)
                                     : (H1g + (size_t)b*9 + (rc6-3)*3);
        u.hr0 = hpr[0]; u.hr1 = hpr[1]; u.hr2 = hpr[2];
        u.sdv = (rc6 < 3) ? vrstd[(size_t)b*3 + rc6] : vtstd[(size_t)b*3 + (rc6-3)];
        u.rsa = (rc6 < 3) ? vrot[(size_t)b*3 + rc6] : vtrans[(size_t)b*3 + (rc6-3)];
        u.rsb = (rc6 < 3) ? prot[(size_t)b*3 + rc6] : ptrans[(size_t)b*3 + (rc6-3)];
        u.velv = vel[(size_t)b*3 + ((r >= 6) ? (r-6) : 0)];
    };
    UP uA, uB;
    load_up(bA, uA);
    load_up(bB, uB);

    float phtRA[6], phtSA[6], phtRB[6], phtSB[6];
    auto pht = [&](const UP& u, const float np[18], const float ncr[9], float* L,
                   float phtR[6], float phtS[6]) {
#pragma unroll
        for (int m = 0; m < 3; ++m) {
            phtR[m] = np[0]*u.h0v[m*3] + np[1]*u.h0v[m*3+1] + np[2]*u.h0v[m*3+2];
            phtS[m] = ncr[0]*u.h0v[m*3] + ncr[1]*u.h0v[m*3+1] + ncr[2]*u.h0v[m*3+2];
        }
#pragma unroll
        for (int m = 3; m < 6; ++m) {
            phtR[m] = np[0]*u.h1v[(m-3)*3] + np[1]*u.h1v[(m-3)*3+1] + np[2]*u.h1v[(m-3)*3+2] + np[m];
            phtS[m] = ncr[0]*u.h1v[(m-3)*3] + ncr[1]*u.h1v[(m-3)*3+1] + ncr[2]*u.h1v[(m-3)*3+2] + ncr[m];
        }
#pragma unroll
        for (int m = 0; m < 6; ++m) {
            L[PHT_OFF + r*8 + m]       = phtR[m];
            L[PHT_OFF + (9 + r)*8 + m] = phtS[m];
        }
    };
    pht(uA, npA, ncrA, LA, phtRA, phtSA);
    pht(uB, npB, ncrB, LB, phtRB, phtSB);
    FENCE_RAW();

    auto s6build = [&](const UP& u, bool valid, const float phtR[6], float* L) {
        if (valid && r < 6) {
            const float VIG = (float)(10.0 / (5.4 * 5.4));
#pragma unroll
            for (int n = 0; n < 6; ++n) {
                float v = u.hr0 * L[PHT_OFF + 0*8 + n] + u.hr1 * L[PHT_OFF + 1*8 + n]
                        + u.hr2 * L[PHT_OFF + 2*8 + n];
                if (r >= 3) v += phtR[n];
                if (n == r) v += VIG * exp10f(3.f * tanhf(u.sdv));
                L[S6_OFF + r*8 + n] = v;
            }
            L[S6_OFF + r*8 + 6] = (r < 3) ? (u.rsa - u.rsb) : (u.rsa * 5.4f - u.rsb);
        }
    };
    s6build(uA, validA, phtRA, LA);
    s6build(uB, validB, phtRB, LB);
    FENCE_RAW();

    // 6x6 solves for A and B run CONCURRENTLY: lane r==0 -> A, lane r==1 -> B
    {
        const bool doSolve = (praw < GPW) && ((r == 0) ? validA : ((r == 1) ? validB : false));
        if (doSolve) {
            float* Sb = (r == 0) ? &LA[S6_OFF] : &LB[S6_OFF];
            float* Yp = (r == 0) ? &LA[Y_OFF] : &LB[Y_OFF];
            float a[6][7];
#pragma unroll
            for (int m = 0; m < 6; ++m) {
                const float4 q0 = *(const float4*)&Sb[m*8];
                const float4 q1 = *(const float4*)&Sb[m*8 + 4];
                a[m][0]=q0.x; a[m][1]=q0.y; a[m][2]=q0.z; a[m][3]=q0.w;
                a[m][4]=q1.x; a[m][5]=q1.y; a[m][6]=q1.z;
            }
#pragma unroll
            for (int k = 0; k < 6; ++k) {
#pragma unroll
                for (int j = k + 1; j < 6; ++j) {
                    const bool c = fabsf(a[j][k]) > fabsf(a[k][k]);
#pragma unroll
                    for (int cc = k; cc < 7; ++cc) {
                        const float hi = c ? a[j][cc] : a[k][cc];
                        const float lo = c ? a[k][cc] : a[j][cc];
                        a[k][cc] = hi; a[j][cc] = lo;
                    }
                }
                const float inv = 1.f / a[k][k];
#pragma unroll
                for (int j = 0; j < 6; ++j) {
                    if (j == k) continue;
                    const float f = a[j][k] * inv;
#pragma unroll
                    for (int cc = k + 1; cc < 7; ++cc) a[j][cc] -= f * a[k][cc];
                }
            }
#pragma unroll
            for (int m = 0; m < 6; ++m) Yp[m] = a[m][6] / a[m][m];
        }
    }
    FENCE_RAW();

    float ymA[6], ymB[6];
#pragma unroll
    for (int m = 0; m < 6; ++m) { ymA[m] = LA[Y_OFF + m]; ymB[m] = LB[Y_OFF + m]; }
    float estrA = 0.f, est9A = 0.f, estrB = 0.f, est9B = 0.f;
#pragma unroll
    for (int m = 0; m < 6; ++m) {
        estrA += phtRA[m]*ymA[m]; est9A += phtSA[m]*ymA[m];
        estrB += phtRB[m]*ymB[m]; est9B += phtSB[m]*ymB[m];
    }
    if (validA) LA[EST_OFF + r] = estrA;
    if (validB) LB[EST_OFF + r] = estrB;
    FENCE_RAW();

    {
        const float e0 = LA[EST_OFF + 0], e1 = LA[EST_OFF + 1], e2 = LA[EST_OFF + 2];
        if (validA) {
            float o;
            if (r < 3)      o = uA.rsb + uA.hr0*e0 + uA.hr1*e1 + uA.hr2*e2;
            else if (r < 6) o = uA.rsb + uA.hr0*e0 + uA.hr1*e1 + uA.hr2*e2 + estrA;
            else            o = uA.velv + estrA;
            out[(size_t)bA*12 + r] = o;
            if (r < 3) out[(size_t)bA*12 + 9 + r] = ((r==0)?gA0:((r==1)?gA1:gA2)) + est9A;
        }
    }
    {
        const float e0 = LB[EST_OFF + 0], e1 = LB[EST_OFF + 1], e2 = LB[EST_OFF + 2];
        if (validB) {
            float o;
            if (r < 3)      o = uB.rsb + uB.hr0*e0 + uB.hr1*e1 + uB.hr2*e2;
            else if (r < 6) o = uB.rsb + uB.hr0*e0 + uB.hr1*e1 + uB.hr2*e2 + estrB;
            else            o = uB.velv + estrB;
            out[(size_t)bB*12 + r] = o;
            if (r < 3) out[(size_t)bB*12 + 9 + r] = ((r==0)?gB0:((r==1)?gB1:gB2)) + est9B;
        }
    }
}

extern "C" void kernel_launch(void* const* d_in, const int* in_sizes, int n_in,
                              void* d_out, int out_size, void* d_ws, size_t ws_size,
                              hipStream_t stream) {
    const float* dts    = (const float*)d_in[0];
    const float* wa     = (const float*)d_in[1];
    const float* Rc     = (const float*)d_in[2];
    const float* vel    = (const float*)d_in[3];
    const float* grav   = (const float*)d_in[4];
    const float* H0g    = (const float*)d_in[5];
    const float* H1g    = (const float*)d_in[6];
    const float* prot   = (const float*)d_in[7];
    const float* ptrans = (const float*)d_in[8];
    const float* vrot   = (const float*)d_in[9];
    const float* vtrans = (const float*)d_in[10];
    const float* vrstd  = (const float*)d_in[11];
    const float* vtstd  = (const float*)d_in[12];
    const float* icds   = (const float*)d_in[13];
    const float* inw    = (const float*)d_in[14];
    float* outp = (float*)d_out;

    const int B = in_sizes[0] / TSTEPS;
    const int grid = (B + PPB - 1) / PPB;
    hipLaunchKernelGGL(ekf_kernel, dim3(grid), dim3(64), 0, stream,
                       dts, wa, Rc, vel, grav, H0g, H1g, prot, ptrans,
                       vrot, vtrans, vrstd, vtstd, icds, inw, outp, B);
}

// Round 13
// 34.289 us; speedup vs baseline: 1.2474x; 1.2474x over previous
//
#include <hip/hip_runtime.h>
#include <math.h>

#define TSTEPS 11
#define PPB 7          // problems per 64-thread wave (block == ONE wave)
#define LPP 9
#define IN_STRIDE 228  // floats per input slot (228%32=4 -> bank stagger); step t at t*20
#define WSTRIDE 228
#define PHT_OFF 0
#define S6_OFF 144
#define Y_OFF 192
#define EST_OFF 200

// single-wave block: RAW needs wave-level lgkmcnt drain; WAR only a compiler fence
#define FENCE_RAW() asm volatile("s_waitcnt lgkmcnt(0)" ::: "memory")
#define FENCE_WAR() asm volatile("" ::: "memory")

__device__ __forceinline__ float sel3(int c, float a, float b, float d) {
    float t = (c == 1) ? b : a;
    return (c == 2) ? d : t;
}
__device__ __forceinline__ size_t umin_sz(size_t a, size_t b) { return a < b ? a : b; }

__global__ void __launch_bounds__(64)
ekf_kernel(const float* __restrict__ dts, const float* __restrict__ wa,
           const float* __restrict__ Rc, const float* __restrict__ vel,
           const float* __restrict__ grav, const float* __restrict__ H0g,
           const float* __restrict__ H1g, const float* __restrict__ prot,
           const float* __restrict__ ptrans, const float* __restrict__ vrot,
           const float* __restrict__ vtrans, const float* __restrict__ vrstd,
           const float* __restrict__ vtstd, const float* __restrict__ icds,
           const float* __restrict__ inw, float* __restrict__ out, int B)
{
    __shared__ __align__(16) float gin[PPB * IN_STRIDE];
    __shared__ __align__(16) float lds[PPB * WSTRIDE];
    const int tid = threadIdx.x;
    const int praw = tid / LPP;
    const int r = tid - praw * LPP;            // 0..8
    const int p = (praw < PPB) ? praw : (PPB - 1);
    const int blk0 = blockIdx.x * PPB;
    const int b0 = blk0 + p;
    const bool valid = (praw < PPB) && (b0 < B);
    const int b = (b0 < B) ? b0 : (B - 1);
    float* L = lds + p * WSTRIDE;
    const float* gi = gin + p * IN_STRIDE;

    // ---- block-coalesced preload of step inputs into re-packed LDS slots (rolled)
    {
        const size_t dmax = (size_t)B * 11 - 1;
#pragma unroll 1
        for (int e = tid; e < PPB * 11; e += 64) {
            const int pp = e / 11, o = e - pp * 11;
            gin[pp * IN_STRIDE + o * 20] = dts[umin_sz((size_t)blk0 * 11 + e, dmax)];
        }
        const size_t wmax = (size_t)B * 72 - 1;
#pragma unroll 1
        for (int e = tid; e < PPB * 66; e += 64) {           // 11 steps x 6
            const int pp = e / 66, o = e - pp * 66;
            const int t = o / 6, k = o - t * 6;
            gin[pp * IN_STRIDE + t * 20 + 2 + k] =
                wa[umin_sz((size_t)blk0 * 72 + (size_t)pp * 72 + o, wmax)];
        }
        const size_t rmax = (size_t)B * 108 - 1;
#pragma unroll 1
        for (int e = tid; e < PPB * 99; e += 64) {           // 11 steps x 9
            const int pp = e / 99, o = e - pp * 99;
            const int t = o / 9, k = o - t * 9;
            gin[pp * IN_STRIDE + t * 20 + 8 + k] =
                Rc[umin_sz((size_t)blk0 * 108 + (size_t)pp * 108 + o, rmax)];
        }
    }

    // ---- preload update-phase operands into registers (latency hidden under scan)
    float h0v[9], h1v[9];
#pragma unroll
    for (int i = 0; i < 9; ++i) { h0v[i] = H0g[(size_t)b * 9 + i]; h1v[i] = H1g[(size_t)b * 9 + i]; }
    const int rc6 = (r < 6) ? r : 5;
    const float* hpr = (rc6 < 3) ? (H0g + (size_t)b * 9 + rc6 * 3)
                                 : (H1g + (size_t)b * 9 + (rc6 - 3) * 3);
    const float hr0 = hpr[0], hr1 = hpr[1], hr2 = hpr[2];
    const float sdv = (rc6 < 3) ? vrstd[(size_t)b * 3 + rc6] : vtstd[(size_t)b * 3 + (rc6 - 3)];
    const float rsa = (rc6 < 3) ? vrot[(size_t)b * 3 + rc6] : vtrans[(size_t)b * 3 + (rc6 - 3)];
    const float rsb = (rc6 < 3) ? prot[(size_t)b * 3 + rc6] : ptrans[(size_t)b * 3 + (rc6 - 3)];
    const float velv = vel[(size_t)b * 3 + ((r >= 6) ? (r - 6) : 0)];

    const float qcA = 1e-7f * exp10f(4.f * tanhf(inw[0]));
    const float qcB = 1e-7f * exp10f(4.f * tanhf(inw[1]));
    const float qcC = 1e-2f * exp10f(4.f * tanhf(inw[2]));
    const float qcD = 1e-3f * exp10f(4.f * tanhf(inw[3]));

    const float g0 = grav[(size_t)b*3+0], g1 = grav[(size_t)b*3+1], g2 = grav[(size_t)b*3+2];

    // Lane state: np = P[:, r]; ncr = P[0:9, 9+r]; d_br = P[9+r][9+r]
    float np[18], ncr[9];
#pragma unroll
    for (int k = 0; k < 18; ++k) np[k] = 0.f;
#pragma unroll
    for (int k = 0; k < 9; ++k) ncr[k] = 0.f;
    float d_br;
    { const float d0 = icds[r];     np[r] = d0*d0 + 1e-12f;
      const float d1 = icds[9 + r]; d_br  = d1*d1 + 1e-12f; }

    const int cls = (r < 3) ? 0 : ((r < 6) ? 1 : 2);
    const int c3 = r - 3 * cls;

    FENCE_RAW();   // staging visible (single-wave block)

    // ===== scan: ROLLED loop (unroll 1) so the body fits I$ =====
#pragma unroll 1
    for (int t = 0; t < TSTEPS; ++t) {
        const int o = t * 20;
        const float dt = gi[o];
        const float2 qa = *(const float2*)&gi[o + 2];
        const float2 qb = *(const float2*)&gi[o + 4];
        const float2 qc = *(const float2*)&gi[o + 6];
        const float w0 = qa.x, w1 = qa.y, w2 = qb.x;
        const float ar0 = qb.y, ar1 = qc.x, ar2 = qc.y;
        float Rm[9];
        {
            const float4 r0 = *(const float4*)&gi[o + 8];
            const float4 r1 = *(const float4*)&gi[o + 12];
            Rm[0]=r0.x; Rm[1]=r0.y; Rm[2]=r0.z; Rm[3]=r0.w;
            Rm[4]=r1.x; Rm[5]=r1.y; Rm[6]=r1.z; Rm[7]=r1.w;
            Rm[8]=gi[o + 16];
        }

        const float hdt2 = 0.5f * dt * dt;
        const float Rg0 = Rm[0]*g0 + Rm[3]*g1 + Rm[6]*g2;
        const float Rg1 = Rm[1]*g0 + Rm[4]*g1 + Rm[7]*g2;
        const float Rg2 = Rm[2]*g0 + Rm[5]*g1 + Rm[8]*g2;
        const float a0 = Rg0 + (ar0 - Rg0);
        const float a1 = Rg1 + (ar1 - Rg1);
        const float a2 = Rg2 + (ar2 - Rg2);

        const float p0 = dt*w0, p1 = dt*w1, p2 = dt*w2;
        const float th2 = p0*p0 + p1*p1 + p2*p2;
        const float th4 = th2 * th2;
        const float A  = 1.f - th2*(1.f/6.f)  + th4*(1.f/120.f);
        const float Bc = 0.5f - th2*(1.f/24.f) + th4*(1.f/720.f);
        float E[9];
        E[0] =  Bc*(p0*p0 - th2);  E[1] =  A*p2 + Bc*p0*p1;  E[2] = -A*p1 + Bc*p0*p2;
        E[3] = -A*p2 + Bc*p1*p0;   E[4] =  Bc*(p1*p1 - th2); E[5] =  A*p0 + Bc*p1*p2;
        E[6] =  A*p1 + Bc*p2*p0;   E[7] = -A*p0 + Bc*p2*p1;  E[8] =  Bc*(p2*p2 - th2);
        float N[9];
        N[0] = -(Rm[1]*a2 - Rm[2]*a1);  N[1] = -(Rm[2]*a0 - Rm[0]*a2);  N[2] = -(Rm[0]*a1 - Rm[1]*a0);
        N[3] = -(Rm[4]*a2 - Rm[5]*a1);  N[4] = -(Rm[5]*a0 - Rm[3]*a2);  N[5] = -(Rm[3]*a1 - Rm[4]*a0);
        N[6] = -(Rm[7]*a2 - Rm[8]*a1);  N[7] = -(Rm[8]*a0 - Rm[6]*a2);  N[8] = -(Rm[6]*a1 - Rm[7]*a0);
        float M2[9];
#pragma unroll
        for (int c = 0; c < 3; ++c) {
            const float n0 = N[c*3], n1 = N[c*3+1], n2 = N[c*3+2];
            M2[c*3+0] = dt*n0 - hdt2*(n1*w2 - n2*w1);
            M2[c*3+1] = dt*n1 - hdt2*(n2*w0 - n0*w2);
            M2[c*3+2] = dt*n2 - hdt2*(n0*w1 - n1*w0);
        }

        auto Smv = [&](const float v[18], float ov[9]) {
            const float ev0 = E[0]*v[0] + E[1]*v[1] + E[2]*v[2];
            const float ev1 = E[3]*v[0] + E[4]*v[1] + E[5]*v[2];
            const float ev2 = E[6]*v[0] + E[7]*v[1] + E[8]*v[2];
            const float cx0 = w1*v[14] - w2*v[13];
            const float cx1 = w2*v[12] - w0*v[14];
            const float cx2 = w0*v[13] - w1*v[12];
            ov[0] = ev0 - dt*v[12] + hdt2*cx0;
            ov[1] = ev1 - dt*v[13] + hdt2*cx1;
            ov[2] = ev2 - dt*v[14] + hdt2*cx2;
            const float nv0 = N[0]*v[0] + N[1]*v[1] + N[2]*v[2];
            const float nv1 = N[3]*v[0] + N[4]*v[1] + N[5]*v[2];
            const float nv2 = N[6]*v[0] + N[7]*v[1] + N[8]*v[2];
            const float rv0 = Rm[0]*v[15] + Rm[1]*v[16] + Rm[2]*v[17];
            const float rv1 = Rm[3]*v[15] + Rm[4]*v[16] + Rm[5]*v[17];
            const float rv2 = Rm[6]*v[15] + Rm[7]*v[16] + Rm[8]*v[17];
            ov[3] = hdt2*nv0 + dt*v[6] - hdt2*v[9]  - hdt2*rv0;
            ov[4] = hdt2*nv1 + dt*v[7] - hdt2*v[10] - hdt2*rv1;
            ov[5] = hdt2*nv2 + dt*v[8] - hdt2*v[11] - hdt2*rv2;
            const float mv0 = M2[0]*v[0] + M2[1]*v[1] + M2[2]*v[2];
            const float mv1 = M2[3]*v[0] + M2[4]*v[1] + M2[5]*v[2];
            const float mv2 = M2[6]*v[0] + M2[7]*v[1] + M2[8]*v[2];
            const float nw0 = N[0]*v[12] + N[1]*v[13] + N[2]*v[14];
            const float nw1 = N[3]*v[12] + N[4]*v[13] + N[5]*v[14];
            const float nw2 = N[6]*v[12] + N[7]*v[13] + N[8]*v[14];
            ov[6] = mv0 - dt*v[9]  - hdt2*nw0 - dt*rv0;
            ov[7] = mv1 - dt*v[10] - hdt2*nw1 - dt*rv1;
            ov[8] = mv2 - dt*v[11] - hdt2*nw2 - dt*rv2;
        };

        // ---- phase A
        float uca[9];
        Smv(np, uca);

        // U column 9+r = S * (ncr ; d_br*e_{9+r})  — bb block diagonal, exact
        float ucb[9];
        {
            const float colR0 = sel3(c3, Rm[0], Rm[1], Rm[2]);
            const float colR1 = sel3(c3, Rm[3], Rm[4], Rm[5]);
            const float colR2 = sel3(c3, Rm[6], Rm[7], Rm[8]);
            const float colN0 = sel3(c3, N[0], N[1], N[2]);
            const float colN1 = sel3(c3, N[3], N[4], N[5]);
            const float colN2 = sel3(c3, N[6], N[7], N[8]);
            const float colK0 = sel3(c3, 0.f, -w2,  w1);
            const float colK1 = sel3(c3,  w2, 0.f, -w0);
            const float colK2 = sel3(c3, -w1,  w0, 0.f);
            const float e0c = (c3 == 0) ? 1.f : 0.f;
            const float e1c = (c3 == 1) ? 1.f : 0.f;
            const float e2c = (c3 == 2) ? 1.f : 0.f;
            const float dbdt = d_br * dt, dbh = d_br * hdt2;

            const float s00 = (cls == 1) ? (-dbdt*e0c + dbh*colK0) : 0.f;
            const float s01 = (cls == 1) ? (-dbdt*e1c + dbh*colK1) : 0.f;
            const float s02 = (cls == 1) ? (-dbdt*e2c + dbh*colK2) : 0.f;
            const float s30 = (cls == 0) ? -dbh*e0c : ((cls == 2) ? -dbh*colR0 : 0.f);
            const float s31 = (cls == 0) ? -dbh*e1c : ((cls == 2) ? -dbh*colR1 : 0.f);
            const float s32 = (cls == 0) ? -dbh*e2c : ((cls == 2) ? -dbh*colR2 : 0.f);
            const float s60 = (cls == 0) ? -dbdt*e0c : ((cls == 1) ? -dbh*colN0 : -dbdt*colR0);
            const float s61 = (cls == 0) ? -dbdt*e1c : ((cls == 1) ? -dbh*colN1 : -dbdt*colR1);
            const float s62 = (cls == 0) ? -dbdt*e2c : ((cls == 1) ? -dbh*colN2 : -dbdt*colR2);

            ucb[0] = E[0]*ncr[0] + E[1]*ncr[1] + E[2]*ncr[2] + s00;
            ucb[1] = E[3]*ncr[0] + E[4]*ncr[1] + E[5]*ncr[2] + s01;
            ucb[2] = E[6]*ncr[0] + E[7]*ncr[1] + E[8]*ncr[2] + s02;
            ucb[3] = hdt2*(N[0]*ncr[0] + N[1]*ncr[1] + N[2]*ncr[2]) + dt*ncr[6] + s30;
            ucb[4] = hdt2*(N[3]*ncr[0] + N[4]*ncr[1] + N[5]*ncr[2]) + dt*ncr[7] + s31;
            ucb[5] = hdt2*(N[6]*ncr[0] + N[7]*ncr[1] + N[8]*ncr[2]) + dt*ncr[8] + s32;
            ucb[6] = M2[0]*ncr[0] + M2[1]*ncr[1] + M2[2]*ncr[2] + s60;
            ucb[7] = M2[3]*ncr[0] + M2[4]*ncr[1] + M2[5]*ncr[2] + s61;
            ucb[8] = M2[6]*ncr[0] + M2[7]*ncr[1] + M2[8]*ncr[2] + s62;
        }

#pragma unroll
        for (int i = 0; i < 9; ++i) {
            L[i*20 + r]     = uca[i];
            L[i*20 + 9 + r] = ucb[i];
        }
        FENCE_RAW();

        // ---- phase B: read U row r
        float ur[18];
        {
            const float4* up = (const float4*)&L[r*20];
            const float4 q0 = up[0], q1 = up[1], q2 = up[2], q3 = up[3];
            const float2 q4 = *(const float2*)&L[r*20 + 16];
            ur[0]=q0.x; ur[1]=q0.y; ur[2]=q0.z; ur[3]=q0.w;
            ur[4]=q1.x; ur[5]=q1.y; ur[6]=q1.z; ur[7]=q1.w;
            ur[8]=q2.x; ur[9]=q2.y; ur[10]=q2.z; ur[11]=q2.w;
            ur[12]=q3.x; ur[13]=q3.y; ur[14]=q3.z; ur[15]=q3.w;
            ur[16]=q4.x; ur[17]=q4.y;
        }

        // Q ≈ G qc Gᵀ dt: col r needs qcC·(R Rᵀ) col for r>=6
        const float rc0 = sel3(c3, Rm[0], Rm[3], Rm[6]);
        const float rc1 = sel3(c3, Rm[1], Rm[4], Rm[7]);
        const float rc2 = sel3(c3, Rm[2], Rm[5], Rm[8]);
        const float dq = dt * qcC;
        const float q0v = dq * (Rm[0]*rc0 + Rm[1]*rc1 + Rm[2]*rc2);
        const float q1v = dq * (Rm[3]*rc0 + Rm[4]*rc1 + Rm[5]*rc2);
        const float q2v = dq * (Rm[6]*rc0 + Rm[7]*rc1 + Rm[8]*rc2);

        // (U Sᵀ)[:,r] = S * (U row r)ᵀ
        float w9[9];
        Smv(ur, w9);

        // ---- assemble new P columns
#pragma unroll
        for (int i = 0; i < 9; ++i)
            np[i] = np[i] + uca[i] + ur[i] + w9[i];
        if (r < 3) np[r] += dt * qcA;
        if (r >= 6) { np[6] += q0v; np[7] += q1v; np[8] += q2v; }
#pragma unroll
        for (int i = 9; i < 18; ++i) np[i] += ur[i];

#pragma unroll
        for (int i = 0; i < 9; ++i) ncr[i] += ucb[i];
        if (r >= 3) d_br += dt * ((r < 6) ? qcB : qcD);

        FENCE_WAR();
    }

    // ---------- update (operands preloaded; P row 9+r = (ncr ; d_br e_r)) ----------
    float phtA[6], phtB[6];
#pragma unroll
    for (int m = 0; m < 3; ++m) {
        phtA[m] = np[0]*h0v[m*3] + np[1]*h0v[m*3+1] + np[2]*h0v[m*3+2];
        phtB[m] = ncr[0]*h0v[m*3] + ncr[1]*h0v[m*3+1] + ncr[2]*h0v[m*3+2];
    }
#pragma unroll
    for (int m = 3; m < 6; ++m) {
        phtA[m] = np[0]*h1v[(m-3)*3] + np[1]*h1v[(m-3)*3+1] + np[2]*h1v[(m-3)*3+2] + np[m];
        phtB[m] = ncr[0]*h1v[(m-3)*3] + ncr[1]*h1v[(m-3)*3+1] + ncr[2]*h1v[(m-3)*3+2] + ncr[m];
    }
#pragma unroll
    for (int m = 0; m < 6; ++m) {
        L[PHT_OFF + r*8 + m]       = phtA[m];
        L[PHT_OFF + (9 + r)*8 + m] = phtB[m];
    }
    FENCE_RAW();

    if (valid && r < 6) {
        const float VIG = (float)(10.0 / (5.4 * 5.4));
#pragma unroll
        for (int n = 0; n < 6; ++n) {
            float v = hr0 * L[PHT_OFF + 0*8 + n] + hr1 * L[PHT_OFF + 1*8 + n]
                    + hr2 * L[PHT_OFF + 2*8 + n];
            if (r >= 3) v += phtA[n];
            if (n == r) v += VIG * exp10f(3.f * tanhf(sdv));
            L[S6_OFF + r*8 + n] = v;
        }
        L[S6_OFF + r*8 + 6] = (r < 3) ? (rsa - rsb) : (rsa * 5.4f - rsb);
    }
    FENCE_RAW();

    // 6x6 solve in registers: lane r==0 per problem (7 per wave, lockstep)
    if (valid && r == 0) {
        float a[6][7];
        const float* Sb = &L[S6_OFF];
#pragma unroll
        for (int m = 0; m < 6; ++m) {
            const float4 q0 = *(const float4*)&Sb[m*8];
            const float4 q1 = *(const float4*)&Sb[m*8 + 4];
            a[m][0]=q0.x; a[m][1]=q0.y; a[m][2]=q0.z; a[m][3]=q0.w;
            a[m][4]=q1.x; a[m][5]=q1.y; a[m][6]=q1.z;
        }
#pragma unroll
        for (int k = 0; k < 6; ++k) {
#pragma unroll
            for (int j = k + 1; j < 6; ++j) {
                const bool c = fabsf(a[j][k]) > fabsf(a[k][k]);
#pragma unroll
                for (int cc = k; cc < 7; ++cc) {
                    const float hi = c ? a[j][cc] : a[k][cc];
                    const float lo = c ? a[k][cc] : a[j][cc];
                    a[k][cc] = hi; a[j][cc] = lo;
                }
            }
            const float inv = 1.f / a[k][k];
#pragma unroll
            for (int j = 0; j < 6; ++j) {
                if (j == k) continue;
                const float f = a[j][k] * inv;
#pragma unroll
                for (int cc = k + 1; cc < 7; ++cc) a[j][cc] -= f * a[k][cc];
            }
        }
#pragma unroll
        for (int m = 0; m < 6; ++m) L[Y_OFF + m] = a[m][6] / a[m][m];
    }
    FENCE_RAW();

    float ym[6];
#pragma unroll
    for (int m = 0; m < 6; ++m) ym[m] = L[Y_OFF + m];
    float estr = 0.f, est9 = 0.f;
#pragma unroll
    for (int m = 0; m < 6; ++m) { estr += phtA[m]*ym[m]; est9 += phtB[m]*ym[m]; }
    if (valid) {
        L[EST_OFF + r] = estr;
        if (r < 3) L[EST_OFF + 9 + r] = est9;
    }
    FENCE_RAW();

    const float e0 = L[EST_OFF + 0], e1 = L[EST_OFF + 1], e2 = L[EST_OFF + 2];
    if (valid) {
        float o;
        if (r < 3) {
            o = rsb + hr0*e0 + hr1*e1 + hr2*e2;
        } else if (r < 6) {
            o = rsb + hr0*e0 + hr1*e1 + hr2*e2 + estr;
        } else {
            o = velv + estr;
        }
        out[(size_t)b*12 + r] = o;
        if (r < 3) out[(size_t)b*12 + 9 + r] = ((r==0)?g0:((r==1)?g1:g2)) + est9;
    }
}

extern "C" void kernel_launch(void* const* d_in, const int* in_sizes, int n_in,
                              void* d_out, int out_size, void* d_ws, size_t ws_size,
                              hipStream_t stream) {
    const float* dts    = (const float*)d_in[0];
    const float* wa     = (const float*)d_in[1];
    const float* Rc     = (const float*)d_in[2];
    const float* vel    = (const float*)d_in[3];
    const float* grav   = (const float*)d_in[4];
    const float* H0g    = (const float*)d_in[5];
    const float* H1g    = (const float*)d_in[6];
    const float* prot   = (const float*)d_in[7];
    const float* ptrans = (const float*)d_in[8];
    const float* vrot   = (const float*)d_in[9];
    const float* vtrans = (const float*)d_in[10];
    const float* vrstd  = (const float*)d_in[11];
    const float* vtstd  = (const float*)d_in[12];
    const float* icds   = (const float*)d_in[13];
    const float* inw    = (const float*)d_in[14];
    float* outp = (float*)d_out;

    const int B = in_sizes[0] / TSTEPS;
    const int grid = (B + PPB - 1) / PPB;
    hipLaunchKernelGGL(ekf_kernel, dim3(grid), dim3(64), 0, stream,
                       dts, wa, Rc, vel, grav, H0g, H1g, prot, ptrans,
                       vrot, vtrans, vrstd, vtstd, icds, inw, outp, B);
}